// Round 2
// baseline (211.213 us; speedup 1.0000x reference)
//
#include <hip/hip_runtime.h>

typedef float    f32x16 __attribute__((ext_vector_type(16)));
typedef _Float16 f16x8  __attribute__((ext_vector_type(8)));

#define NWAVES 4
#define NBLOCKS 1024

// Per edge: raw = concat(zi[src] (64), zj[dst] (64));
// hid = relu(raw @ W1^T + b1) [128]; score = sigmoid(hid . W3 + b3).
// neg_score == pos_score (source bug: both scored from raw_pos).
__global__ __launch_bounds__(256, 4) void graphlp_mfma(
    const float* __restrict__ zi, const float* __restrict__ zj,
    const float* __restrict__ W1, const float* __restrict__ b1p,
    const float* __restrict__ W3, const float* __restrict__ b3p,
    const int* __restrict__ psrc, const int* __restrict__ pdst,
    float* __restrict__ out, const int nEdges, const int nTiles)
{
    // W1 as f16, swizzled: byte = row*256 + ((k*2) ^ ((row&7)<<4)); 32 KiB
    __shared__ uint4 w1s[2048];
    char* lds = reinterpret_cast<char*>(w1s);
    const int tid = threadIdx.x;

    #pragma unroll
    for (int i = 0; i < 8; ++i) {
        const int ch  = tid + i * 256;   // 2048 chunks of 8 f32
        const int row = ch >> 4;         // 0..127 (hidden unit n)
        const int kg  = ch & 15;         // 8-wide k group
        const float* s = W1 + row * 128 + kg * 8;
        const float4 a0 = *reinterpret_cast<const float4*>(s);
        const float4 a1 = *reinterpret_cast<const float4*>(s + 4);
        f16x8 v;
        v[0]=(_Float16)a0.x; v[1]=(_Float16)a0.y; v[2]=(_Float16)a0.z; v[3]=(_Float16)a0.w;
        v[4]=(_Float16)a1.x; v[5]=(_Float16)a1.y; v[6]=(_Float16)a1.z; v[7]=(_Float16)a1.w;
        const int off = row * 256 + ((kg * 16) ^ ((row & 7) << 4));
        *reinterpret_cast<f16x8*>(lds + off) = v;
    }
    __syncthreads();

    const int lane = tid & 63;
    const int wav  = tid >> 6;
    const int lr   = lane & 31;   // edge-row / n-col within 32
    const int lq   = lane >> 5;   // k-half selector

    float b1v[4], w3v[4];
    #pragma unroll
    for (int nb = 0; nb < 4; ++nb) {
        b1v[nb] = b1p[nb * 32 + lr];
        w3v[nb] = W3[nb * 32 + lr];
    }
    const float b3 = b3p[0];

    const int gstride = gridDim.x * NWAVES;
    int g = blockIdx.x * NWAVES + wav;

    // prefetched indices for tile g
    int si = 0, di = 0;
    if (g < nTiles) {
        const int e = min(g * 32 + lr, nEdges - 1);
        si = psrc[e]; di = pdst[e];
    }

    while (g < nTiles) {
        const int gn = g + gstride;
        // prefetch next tile's indices (hide idx->gather dependency)
        int si_n = 0, di_n = 0;
        if (gn < nTiles) {
            const int en = min(gn * 32 + lr, nEdges - 1);
            si_n = psrc[en]; di_n = pdst[en];
        }

        const float* __restrict__ sp = zi + (size_t)si * 64;
        const float* __restrict__ dp = zj + (size_t)di * 64;

        // A fragments: lane holds raw[lr][kk*16 + lq*8 .. +8)
        f16x8 afrag[8];
        #pragma unroll
        for (int kk = 0; kk < 8; ++kk) {
            const int kb = kk * 16 + lq * 8;                 // 0..120, step 8
            const float* p = (kk < 4) ? (sp + kb) : (dp + kb - 64);
            const float4 a0 = *reinterpret_cast<const float4*>(p);
            const float4 a1 = *reinterpret_cast<const float4*>(p + 4);
            f16x8 v;
            v[0]=(_Float16)a0.x; v[1]=(_Float16)a0.y; v[2]=(_Float16)a0.z; v[3]=(_Float16)a0.w;
            v[4]=(_Float16)a1.x; v[5]=(_Float16)a1.y; v[6]=(_Float16)a1.z; v[7]=(_Float16)a1.w;
            afrag[kk] = v;
        }

        float pr[16];
        #pragma unroll
        for (int r = 0; r < 16; ++r) pr[r] = 0.0f;

        // nb processed in pairs: 2x16 acc regs live instead of 4x16
        #pragma unroll
        for (int nbp = 0; nbp < 2; ++nbp) {
            f32x16 acc0, acc1;
            #pragma unroll
            for (int r = 0; r < 16; ++r) { acc0[r] = 0.0f; acc1[r] = 0.0f; }
            const int n0 = (2*nbp)     * 32 + lr;            // W1 rows
            const int n1 = (2*nbp + 1) * 32 + lr;
            #pragma unroll
            for (int kk = 0; kk < 8; ++kk) {
                const int kx = kk * 32 + lq * 16;
                const f16x8 bf0 = *reinterpret_cast<const f16x8*>(
                    lds + n0 * 256 + (kx ^ ((n0 & 7) << 4)));
                const f16x8 bf1 = *reinterpret_cast<const f16x8*>(
                    lds + n1 * 256 + (kx ^ ((n1 & 7) << 4)));
                acc0 = __builtin_amdgcn_mfma_f32_32x32x16_f16(afrag[kk], bf0, acc0, 0, 0, 0);
                acc1 = __builtin_amdgcn_mfma_f32_32x32x16_f16(afrag[kk], bf1, acc1, 0, 0, 0);
            }
            const float bb0 = b1v[2*nbp], bb1 = b1v[2*nbp + 1];
            const float ww0 = w3v[2*nbp], ww1 = w3v[2*nbp + 1];
            #pragma unroll
            for (int r = 0; r < 16; ++r) {
                pr[r] = fmaf(fmaxf(acc0[r] + bb0, 0.0f), ww0, pr[r]);
                pr[r] = fmaf(fmaxf(acc1[r] + bb1, 0.0f), ww1, pr[r]);
            }
        }

        // fold-reduce over the 32 n-lanes: halve reg count each stage
        float p8[8];
        #pragma unroll
        for (int r = 0; r < 8; ++r) {
            const float lo = pr[r], hi = pr[r + 8];
            const float sent = (lane & 1) ? lo : hi;
            const float got  = __shfl_xor(sent, 1);
            p8[r] = ((lane & 1) ? hi : lo) + got;
        }
        float p4[4];
        #pragma unroll
        for (int r = 0; r < 4; ++r) {
            const float lo = p8[r], hi = p8[r + 4];
            const float sent = (lane & 2) ? lo : hi;
            const float got  = __shfl_xor(sent, 2);
            p4[r] = ((lane & 2) ? hi : lo) + got;
        }
        float p2[2];
        #pragma unroll
        for (int r = 0; r < 2; ++r) {
            const float lo = p4[r], hi = p4[r + 2];
            const float sent = (lane & 4) ? lo : hi;
            const float got  = __shfl_xor(sent, 4);
            p2[r] = ((lane & 4) ? hi : lo) + got;
        }
        float p1;
        {
            const float lo = p2[0], hi = p2[1];
            const float sent = (lane & 8) ? lo : hi;
            const float got  = __shfl_xor(sent, 8);
            p1 = ((lane & 8) ? hi : lo) + got;
        }
        p1 += __shfl_xor(p1, 16);

        // lane -> original reg index rid; edge m = (rid&3) + 8*(rid>>2) + 4*lq
        const int rid = 8 * (lane & 1) + 4 * ((lane >> 1) & 1)
                      + 2 * ((lane >> 2) & 1) + ((lane >> 3) & 1);
        const int m  = (rid & 3) + 8 * (rid >> 2) + 4 * lq;
        const int eo = g * 32 + m;
        if (eo < nEdges) {
            const float sc = 1.0f / (1.0f + __expf(-(p1 + b3)));
            if (lane & 16) out[nEdges + eo] = sc;   // neg_score (== pos)
            else           out[eo] = sc;            // pos_score
        }

        g = gn; si = si_n; di = di_n;
    }
}

extern "C" void kernel_launch(void* const* d_in, const int* in_sizes, int n_in,
                              void* d_out, int out_size, void* d_ws, size_t ws_size,
                              hipStream_t stream)
{
    const float* zi = (const float*)d_in[0];
    const float* zj = (const float*)d_in[1];
    // d_in[2] = zn  (unused: neg path is dead code in the reference)
    const float* W1 = (const float*)d_in[3];
    const float* b1 = (const float*)d_in[4];
    const float* W3 = (const float*)d_in[5];
    const float* b3 = (const float*)d_in[6];
    const int* psrc = (const int*)d_in[7];
    const int* pdst = (const int*)d_in[8];
    float* out = (float*)d_out;

    const int nEdges = in_sizes[7];
    const int nTiles = (nEdges + 31) / 32;
    int nBlocks = (nTiles + NWAVES - 1) / NWAVES;
    if (nBlocks > NBLOCKS) nBlocks = NBLOCKS;
    hipLaunchKernelGGL(graphlp_mfma, dim3(nBlocks), dim3(256), 0, stream,
                       zi, zj, W1, b1, W3, b3, psrc, pdst, out, nEdges, nTiles);
}

// Round 4
// 67.931 us; speedup vs baseline: 3.1092x; 3.1092x over previous
//
#include <hip/hip_runtime.h>

typedef float    f32x16 __attribute__((ext_vector_type(16)));
typedef _Float16 f16x8  __attribute__((ext_vector_type(8)));

#define NWAVES 4
#define TPW 4
#define TILES_PER_BLOCK (NWAVES * TPW)

// ---------------- prep: f32 node tables -> f16 tables in d_ws ----------------
__global__ __launch_bounds__(256) void prep_f16(
    const float* __restrict__ zi, const float* __restrict__ zj,
    _Float16* __restrict__ zif, _Float16* __restrict__ zjf, const int nChunkPer)
{
    const int stride = gridDim.x * blockDim.x;
    for (int c = blockIdx.x * blockDim.x + threadIdx.x; c < 2 * nChunkPer; c += stride) {
        const float* s;
        _Float16* d;
        if (c < nChunkPer) { s = zi + (size_t)c * 8; d = zif + (size_t)c * 8; }
        else { s = zj + (size_t)(c - nChunkPer) * 8; d = zjf + (size_t)(c - nChunkPer) * 8; }
        const float4 a0 = *reinterpret_cast<const float4*>(s);
        const float4 a1 = *reinterpret_cast<const float4*>(s + 4);
        f16x8 v;
        v[0]=(_Float16)a0.x; v[1]=(_Float16)a0.y; v[2]=(_Float16)a0.z; v[3]=(_Float16)a0.w;
        v[4]=(_Float16)a1.x; v[5]=(_Float16)a1.y; v[6]=(_Float16)a1.z; v[7]=(_Float16)a1.w;
        *reinterpret_cast<f16x8*>(d) = v;
    }
}

// ---------------- main ----------------
// Per edge: raw = concat(zi[src] (64), zj[dst] (64));
// hid = relu(raw @ W1^T + b1) [128]; score = sigmoid(hid . W3 + b3).
// neg_score == pos_score (source bug: both scored from raw_pos).
template<bool F16TAB>
__global__ __launch_bounds__(256) void graphlp_mfma(
    const float* __restrict__ zi, const float* __restrict__ zj,
    const _Float16* __restrict__ zif, const _Float16* __restrict__ zjf,
    const float* __restrict__ W1, const float* __restrict__ b1p,
    const float* __restrict__ W3, const float* __restrict__ b3p,
    const int* __restrict__ psrc, const int* __restrict__ pdst,
    float* __restrict__ out, const int nEdges, const int nTiles)
{
    // W1 as f16, swizzled: byte = row*256 + ((k*2) ^ ((row&7)<<4)); 32 KiB
    __shared__ uint4 w1s[2048];
    char* lds = reinterpret_cast<char*>(w1s);
    const int tid = threadIdx.x;

    #pragma unroll
    for (int i = 0; i < 8; ++i) {
        const int ch  = tid + i * 256;   // 2048 chunks of 8 f32
        const int row = ch >> 4;         // 0..127 (hidden unit n)
        const int kg  = ch & 15;         // 8-wide k group
        const float* s = W1 + row * 128 + kg * 8;
        const float4 a0 = *reinterpret_cast<const float4*>(s);
        const float4 a1 = *reinterpret_cast<const float4*>(s + 4);
        f16x8 v;
        v[0]=(_Float16)a0.x; v[1]=(_Float16)a0.y; v[2]=(_Float16)a0.z; v[3]=(_Float16)a0.w;
        v[4]=(_Float16)a1.x; v[5]=(_Float16)a1.y; v[6]=(_Float16)a1.z; v[7]=(_Float16)a1.w;
        const int off = row * 256 + ((kg * 16) ^ ((row & 7) << 4));
        *reinterpret_cast<f16x8*>(lds + off) = v;
    }
    __syncthreads();

    const int lane = tid & 63;
    const int wav  = tid >> 6;
    const int lr   = lane & 31;   // edge-row / n-col within 32
    const int lq   = lane >> 5;   // k-half selector

    float b1v[4], w3v[4];
    #pragma unroll
    for (int nb = 0; nb < 4; ++nb) {
        b1v[nb] = b1p[nb * 32 + lr];
        w3v[nb] = W3[nb * 32 + lr];
    }
    const float b3 = b3p[0];

    // consecutive tiles per block (round-1 mapping; grid-stride regressed r2)
    int si = 0, di = 0;
    {
        const int g0 = blockIdx.x * TILES_PER_BLOCK + wav;  // t=0 tile
        if (g0 < nTiles) {
            const int e = min(g0 * 32 + lr, nEdges - 1);
            si = psrc[e]; di = pdst[e];
        }
    }

    for (int t = 0; t < TPW; ++t) {
        const int g = blockIdx.x * TILES_PER_BLOCK + t * NWAVES + wav;
        if (g >= nTiles) break;          // wave-uniform

        // prefetch next tile's indices (hide idx->gather dependency)
        int si_n = 0, di_n = 0;
        if (t + 1 < TPW) {
            const int gn = g + NWAVES;
            if (gn < nTiles) {
                const int en = min(gn * 32 + lr, nEdges - 1);
                si_n = psrc[en]; di_n = pdst[en];
            }
        }

        // A fragments: lane holds raw[lr][kk*16 + lq*8 .. +8)
        f16x8 afrag[8];
        if constexpr (F16TAB) {
            const _Float16* __restrict__ sp = zif + (size_t)si * 64;
            const _Float16* __restrict__ dp = zjf + (size_t)di * 64;
            #pragma unroll
            for (int kk = 0; kk < 4; ++kk) {
                afrag[kk]     = *reinterpret_cast<const f16x8*>(sp + kk * 16 + lq * 8);
                afrag[kk + 4] = *reinterpret_cast<const f16x8*>(dp + kk * 16 + lq * 8);
            }
        } else {
            const float* __restrict__ sp = zi + (size_t)si * 64;
            const float* __restrict__ dp = zj + (size_t)di * 64;
            #pragma unroll
            for (int kk = 0; kk < 8; ++kk) {
                const int kb = kk * 16 + lq * 8;             // 0..120, step 8
                const float* p = (kk < 4) ? (sp + kb) : (dp + kb - 64);
                const float4 a0 = *reinterpret_cast<const float4*>(p);
                const float4 a1 = *reinterpret_cast<const float4*>(p + 4);
                f16x8 v;
                v[0]=(_Float16)a0.x; v[1]=(_Float16)a0.y; v[2]=(_Float16)a0.z; v[3]=(_Float16)a0.w;
                v[4]=(_Float16)a1.x; v[5]=(_Float16)a1.y; v[6]=(_Float16)a1.z; v[7]=(_Float16)a1.w;
                afrag[kk] = v;
            }
        }

        float pr[16];
        #pragma unroll
        for (int r = 0; r < 16; ++r) pr[r] = 0.0f;

        // nb processed in pairs: 2x16 acc regs live instead of 4x16
        #pragma unroll
        for (int nbp = 0; nbp < 2; ++nbp) {
            f32x16 acc0, acc1;
            #pragma unroll
            for (int r = 0; r < 16; ++r) { acc0[r] = 0.0f; acc1[r] = 0.0f; }
            const int n0 = (2*nbp)     * 32 + lr;            // W1 rows
            const int n1 = (2*nbp + 1) * 32 + lr;
            #pragma unroll
            for (int kk = 0; kk < 8; ++kk) {
                const int kx = kk * 32 + lq * 16;
                const f16x8 bf0 = *reinterpret_cast<const f16x8*>(
                    lds + n0 * 256 + (kx ^ ((n0 & 7) << 4)));
                const f16x8 bf1 = *reinterpret_cast<const f16x8*>(
                    lds + n1 * 256 + (kx ^ ((n1 & 7) << 4)));
                acc0 = __builtin_amdgcn_mfma_f32_32x32x16_f16(afrag[kk], bf0, acc0, 0, 0, 0);
                acc1 = __builtin_amdgcn_mfma_f32_32x32x16_f16(afrag[kk], bf1, acc1, 0, 0, 0);
            }
            const float bb0 = b1v[2*nbp], bb1 = b1v[2*nbp + 1];
            const float ww0 = w3v[2*nbp], ww1 = w3v[2*nbp + 1];
            #pragma unroll
            for (int r = 0; r < 16; ++r) {
                pr[r] = fmaf(fmaxf(acc0[r] + bb0, 0.0f), ww0, pr[r]);
                pr[r] = fmaf(fmaxf(acc1[r] + bb1, 0.0f), ww1, pr[r]);
            }
        }

        // fold-reduce over the 32 n-lanes: halve reg count each stage
        float p8[8];
        #pragma unroll
        for (int r = 0; r < 8; ++r) {
            const float lo = pr[r], hi = pr[r + 8];
            const float sent = (lane & 1) ? lo : hi;
            const float got  = __shfl_xor(sent, 1);
            p8[r] = ((lane & 1) ? hi : lo) + got;
        }
        float p4[4];
        #pragma unroll
        for (int r = 0; r < 4; ++r) {
            const float lo = p8[r], hi = p8[r + 4];
            const float sent = (lane & 2) ? lo : hi;
            const float got  = __shfl_xor(sent, 2);
            p4[r] = ((lane & 2) ? hi : lo) + got;
        }
        float p2[2];
        #pragma unroll
        for (int r = 0; r < 2; ++r) {
            const float lo = p4[r], hi = p4[r + 2];
            const float sent = (lane & 4) ? lo : hi;
            const float got  = __shfl_xor(sent, 4);
            p2[r] = ((lane & 4) ? hi : lo) + got;
        }
        float p1;
        {
            const float lo = p2[0], hi = p2[1];
            const float sent = (lane & 8) ? lo : hi;
            const float got  = __shfl_xor(sent, 8);
            p1 = ((lane & 8) ? hi : lo) + got;
        }
        p1 += __shfl_xor(p1, 16);

        // lane -> original reg index rid; edge m = (rid&3) + 8*(rid>>2) + 4*lq
        const int rid = 8 * (lane & 1) + 4 * ((lane >> 1) & 1)
                      + 2 * ((lane >> 2) & 1) + ((lane >> 3) & 1);
        const int m  = (rid & 3) + 8 * (rid >> 2) + 4 * lq;
        const int eo = g * 32 + m;
        if (eo < nEdges) {
            const float sc = 1.0f / (1.0f + __expf(-(p1 + b3)));
            if (lane & 16) out[nEdges + eo] = sc;   // neg_score (== pos)
            else           out[eo] = sc;            // pos_score
        }

        si = si_n; di = di_n;
    }
}

extern "C" void kernel_launch(void* const* d_in, const int* in_sizes, int n_in,
                              void* d_out, int out_size, void* d_ws, size_t ws_size,
                              hipStream_t stream)
{
    const float* zi = (const float*)d_in[0];
    const float* zj = (const float*)d_in[1];
    // d_in[2] = zn  (unused: neg path is dead code in the reference)
    const float* W1 = (const float*)d_in[3];
    const float* b1 = (const float*)d_in[4];
    const float* W3 = (const float*)d_in[5];
    const float* b3 = (const float*)d_in[6];
    const int* psrc = (const int*)d_in[7];
    const int* pdst = (const int*)d_in[8];
    float* out = (float*)d_out;

    const int nEdges = in_sizes[7];
    const int nNodesI = in_sizes[0] / 64;   // zi rows
    const int nNodesJ = in_sizes[1] / 64;   // zj rows
    const int nTiles = (nEdges + 31) / 32;
    const int nBlocks = (nTiles + TILES_PER_BLOCK - 1) / TILES_PER_BLOCK;

    const size_t bytesI = (size_t)nNodesI * 64 * sizeof(_Float16);
    const size_t bytesJ = (size_t)nNodesJ * 64 * sizeof(_Float16);
    const bool useF16 = (ws_size >= bytesI + bytesJ) && (nNodesI == nNodesJ);

    if (useF16) {
        _Float16* zif = (_Float16*)d_ws;
        _Float16* zjf = (_Float16*)((char*)d_ws + bytesI);
        const int nChunkPer = nNodesI * 64 / 8;
        hipLaunchKernelGGL(prep_f16, dim3(2048), dim3(256), 0, stream,
                           zi, zj, zif, zjf, nChunkPer);
        hipLaunchKernelGGL((graphlp_mfma<true>), dim3(nBlocks), dim3(256), 0, stream,
                           zi, zj, zif, zjf, W1, b1, W3, b3, psrc, pdst,
                           out, nEdges, nTiles);
    } else {
        hipLaunchKernelGGL((graphlp_mfma<false>), dim3(nBlocks), dim3(256), 0, stream,
                           zi, zj, (const _Float16*)nullptr, (const _Float16*)nullptr,
                           W1, b1, W3, b3, psrc, pdst, out, nEdges, nTiles);
    }
}